// Round 10
// baseline (1986.979 us; speedup 1.0000x reference)
//
#include <hip/hip_runtime.h>
#include <hip/hip_bf16.h>

#define NPTS   8192
#define NBATCH 8
#define S      1024
#define K      16
#define D      64
#define CIN    67
#define WN     16
#define OUTC   128

// d_out layout (floats): [0,24576) new_xyz [B,3,S]; [24576, 24576+1048576) out [B,128,S];
// [1073152, 1081344) fps_idx as float [B,S]
#define OUT_MAIN 24576
#define OUT_FPS  1073152

// ticket-role boundaries (arrival order == topological order; workers are
// readiness-ordered: unit u -> batch u&7, chunk u>>3)
#define T_FPS   0
#define T_TP    8
#define T_WK    1032
#define NBLK    1544

#define SCOPE __HIP_MEMORY_SCOPE_AGENT

struct Ctrl {
  int ticket;
  int pad0[31];
  int tp_done[8];      // transpose blocks done per batch (128 = all)
  int pad1[24];
  int prog[8];         // FPS publication progress (centroids) per batch
};

__device__ __forceinline__ unsigned long long aload64(const unsigned long long* p) {
  return __hip_atomic_load(p, __ATOMIC_RELAXED, SCOPE);
}
__device__ __forceinline__ void astore64(unsigned long long* p, unsigned long long v) {
  __hip_atomic_store(p, v, __ATOMIC_RELAXED, SCOPE);
}

// Block barrier waiting only on LDS ops (publication stores stay in flight).
__device__ __forceinline__ void barrier_lgkm() {
  asm volatile("s_waitcnt lgkmcnt(0)\n\ts_barrier" ::: "memory");
}

// DPP pair-max step: (key,pos) accumulate toward lane 63. bound_ctrl=true ->
// invalid lanes contribute key=0 (never wins: key low32 = ~idx > 0 always).
template <int CTRL, int RM>
__device__ __forceinline__ void dpp_max_pair(unsigned long long& key, int& pos) {
  int lo = __builtin_amdgcn_update_dpp(0, (int)(unsigned)(key & 0xFFFFFFFFull), CTRL, RM, 0xF, true);
  int hi = __builtin_amdgcn_update_dpp(0, (int)(unsigned)(key >> 32),           CTRL, RM, 0xF, true);
  int op = __builtin_amdgcn_update_dpp(0, pos,                                  CTRL, RM, 0xF, true);
  unsigned long long o = ((unsigned long long)(unsigned)hi << 32) | (unsigned)lo;
  if (o > key) { key = o; pos = op; }
}

// ---------------------------------------------------------------- FPS producer
// Exact bucketed FPS: points counting-sorted into 128 spatial buckets of 64
// (grid-cell order). Per iter: (A) per-bucket conservative lower bound of
// d(.,c) vs bucket max-dist -> exact skip (margin 1e-6 >> 8 ulp error bound,
// so a skipped bucket provably has min(dist,d)=dist for every point);
// (B) update dirty buckets' points (LDS float4 x,y,z,dist), group-reduce
// bucket max key (dist_bits<<32|~orig_idx -- exact reference tie-break);
// (C) one-wave DPP pair-max over 128 bucket keys -> winner coords via LDS.
// Outputs stream through a 64-deep ring, flushed every 32 iters fire-and-forget.
__device__ void fps_role(int b, const float* __restrict__ xyz,
                         unsigned long long* __restrict__ nxA,
                         unsigned long long* __restrict__ nxB,
                         float* __restrict__ out, Ctrl* ctrl, void* smem)
{
#pragma clang fp contract(off)
  char* bp = (char*)smem;
  float4*             sp4   = (float4*)bp;                          // [8192] 131072 B
  unsigned short*     sidx  = (unsigned short*)(bp + 131072);       // [8192]  16384 B
  float*              bbox  = (float*)(bp + 147456);                // [128*6]  3072 B
  unsigned long long* bkey  = (unsigned long long*)(bp + 150528);   // [128]    1024 B
  int*                bpos  = (int*)(bp + 151552);                  // [128]     512 B
  int*                dlist = (int*)(bp + 152064);                  // [128]     512 B
  int*                cnt   = (int*)(bp + 152576);                  // [2]
  unsigned long long* skey  = (unsigned long long*)(bp + 152592);   // [2]
  int*                sposl = (int*)(bp + 152608);                  // [2]
  float4*             ring  = (float4*)(bp + 152624);               // [64]     1024 B
  // init-only overlays (regions rewritten after scatter):
  int* hist = (int*)(bp + 147456);                                  // [512]
  int* offs = (int*)(bp + 149504);                                  // [512]

  const int tid  = threadIdx.x;
  const int wave = tid >> 6;
  const int lane = tid & 63;
  const float* xb = xyz + (size_t)b * 3 * NPTS;

  // ---- init: load, block bbox, grid-cell counting sort, bucket bboxes
  float px[16], py[16], pz[16];
  int   cid[16];
#pragma unroll
  for (int i = 0; i < 16; i++) {
    int n = i * 512 + tid;
    px[i] = xb[n]; py[i] = xb[NPTS + n]; pz[i] = xb[2 * NPTS + n];
  }
  float mnx = px[0], mxx = px[0], mny = py[0], mxy = py[0], mnz = pz[0], mxz = pz[0];
#pragma unroll
  for (int i = 1; i < 16; i++) {
    mnx = fminf(mnx, px[i]); mxx = fmaxf(mxx, px[i]);
    mny = fminf(mny, py[i]); mxy = fmaxf(mxy, py[i]);
    mnz = fminf(mnz, pz[i]); mxz = fmaxf(mxz, pz[i]);
  }
#pragma unroll
  for (int off = 1; off < 64; off <<= 1) {
    mnx = fminf(mnx, __shfl_xor(mnx, off)); mxx = fmaxf(mxx, __shfl_xor(mxx, off));
    mny = fminf(mny, __shfl_xor(mny, off)); mxy = fmaxf(mxy, __shfl_xor(mxy, off));
    mnz = fminf(mnz, __shfl_xor(mnz, off)); mxz = fmaxf(mxz, __shfl_xor(mxz, off));
  }
  if (lane == 0) {
    ring[wave]     = make_float4(mnx, mxx, mny, mxy);
    ring[8 + wave] = make_float4(mnz, mxz, 0.f, 0.f);
  }
  if (tid < 512) hist[tid] = 0;
  __syncthreads();
  float LX = ring[0].x, HX = ring[0].y, LY = ring[0].z, HY = ring[0].w;
  float LZ = ring[8].x, HZ = ring[8].y;
#pragma unroll
  for (int w = 1; w < 8; w++) {
    LX = fminf(LX, ring[w].x); HX = fmaxf(HX, ring[w].y);
    LY = fminf(LY, ring[w].z); HY = fmaxf(HY, ring[w].w);
    LZ = fminf(LZ, ring[8 + w].x); HZ = fmaxf(HZ, ring[8 + w].y);
  }
  const float sx = 7.999f / fmaxf(HX - LX, 1e-30f);
  const float sy = 7.999f / fmaxf(HY - LY, 1e-30f);
  const float sz = 7.999f / fmaxf(HZ - LZ, 1e-30f);
#pragma unroll
  for (int i = 0; i < 16; i++) {
    int ix = min(7, max(0, (int)((px[i] - LX) * sx)));
    int iy = min(7, max(0, (int)((py[i] - LY) * sy)));
    int iz = min(7, max(0, (int)((pz[i] - LZ) * sz)));
    cid[i] = (iz << 6) | (iy << 3) | ix;
    atomicAdd(&hist[cid[i]], 1);
  }
  __syncthreads();
  if (tid < 512) {                       // serial exclusive prefix (once, ~1us)
    int s = 0;
    for (int k = 0; k < tid; k++) s += hist[k];
    offs[tid] = s;
  }
  __syncthreads();
#pragma unroll
  for (int i = 0; i < 16; i++) {
    int slot = atomicAdd(&offs[cid[i]], 1);
    sp4[slot]  = make_float4(px[i], py[i], pz[i], 1e10f);
    sidx[slot] = (unsigned short)(i * 512 + tid);
  }
  __syncthreads();
  if (tid < 128) {                       // bucket bboxes over 64 sorted points
    float lx = 3.4e38f, hx = -3.4e38f, ly = 3.4e38f, hy = -3.4e38f, lz = 3.4e38f, hz = -3.4e38f;
    for (int m = 0; m < 64; m++) {
      float4 P = sp4[tid * 64 + m];
      lx = fminf(lx, P.x); hx = fmaxf(hx, P.x);
      ly = fminf(ly, P.y); hy = fmaxf(hy, P.y);
      lz = fminf(lz, P.z); hz = fmaxf(hz, P.z);
    }
    bbox[tid * 6 + 0] = lx; bbox[tid * 6 + 1] = hx;
    bbox[tid * 6 + 2] = ly; bbox[tid * 6 + 3] = hy;
    bbox[tid * 6 + 4] = lz; bbox[tid * 6 + 5] = hz;
    bkey[tid] = (unsigned long long)0x7F7FFFFFu << 32;   // maxd=3.4e38 -> force dirty
    bpos[tid] = 0;
  }
  if (tid == 0) cnt[0] = 0;
  __syncthreads();

  int far = 0;
  float cx = xb[0], cy = xb[NPTS], cz = xb[2 * NPTS];

  for (int t = 0; t < 1024; t++) {
    const int parity = t & 1;
    if (tid == (t & 511)) {
      ring[t & 63] = make_float4(cx, cy, cz, (float)far);
      cnt[parity ^ 1] = 0;               // re-arm counter for next iter
    }
    // flush previous 32 selections (fire-and-forget; lgkm barriers never drain)
    if ((t & 31) == 0 && t > 0 && wave == 0 && lane < 32) {
      int tt = t - 32 + lane;
      float4 h = ring[tt & 63];
      int gidx = (b << 10) + tt;
      out[OUT_FPS + b * 1024 + tt] = h.w;
      out[b * 3072 + tt]           = h.x;
      out[b * 3072 + 1024 + tt]    = h.y;
      out[b * 3072 + 2048 + tt]    = h.z;
      astore64(&nxA[gidx],
               ((unsigned long long)__float_as_uint(h.x) << 32) | __float_as_uint(h.y));
      astore64(&nxB[gidx],
               ((unsigned long long)__float_as_uint(h.z) << 32) | (unsigned)((int)h.w + 1));
      if (lane == 0)
        __hip_atomic_store(&ctrl->prog[b], t, __ATOMIC_RELAXED, SCOPE);
    }

    // ---- phase A: exact bucket skip test
    if (tid < 128) {
      float maxd = __uint_as_float((unsigned)(bkey[tid] >> 32));
      float ux = fmaxf(0.f, fmaxf(bbox[tid * 6 + 0] - cx, cx - bbox[tid * 6 + 1]));
      float uy = fmaxf(0.f, fmaxf(bbox[tid * 6 + 2] - cy, cy - bbox[tid * 6 + 3]));
      float uz = fmaxf(0.f, fmaxf(bbox[tid * 6 + 4] - cz, cz - bbox[tid * 6 + 5]));
      float lb = (ux * ux + uy * uy) + uz * uz;
      if (lb * 0.999999f < maxd) {       // conservative: margin >> fp error bound
        int s = atomicAdd(&cnt[parity], 1);
        dlist[s] = tid;
      }
    }
    barrier_lgkm();

    // ---- phase B: update dirty buckets (8 threads x 8 pts per bucket)
    const int Dn = cnt[parity];
    for (int p = 0; p * 64 < Dn; p++) {
      int g = p * 64 + (tid >> 3);
      if (g < Dn) {
        int j = dlist[g];
        int base = j * 64 + (tid & 7) * 8;
        uint4 iw = *(const uint4*)(sidx + base);     // 8 orig idx (u16), 16B aligned
        unsigned long long gk = 0; int gp = 0;
#pragma unroll
        for (int m = 0; m < 8; m++) {
          float4 P = sp4[base + m];
          float dx = P.x - cx, dy = P.y - cy, dz = P.z - cz;
          float d  = (dx * dx + dy * dy) + dz * dz;
          float nd = fminf(P.w, d);
          ((float*)&sp4[base + m])[3] = nd;
          unsigned oi = (((const unsigned*)&iw)[m >> 1] >> ((m & 1) * 16)) & 0xFFFFu;
          unsigned long long key =
              ((unsigned long long)__float_as_uint(nd) << 32) | (unsigned)(~oi);
          if (key > gk) { gk = key; gp = base + m; }
        }
#pragma unroll
        for (int w = 1; w < 8; w <<= 1) {            // 8-lane group reduce
          unsigned long long ok = __shfl_xor(gk, w, 8);
          int op = __shfl_xor(gp, w, 8);
          if (ok > gk) { gk = ok; gp = op; }
        }
        if ((tid & 7) == 0) { bkey[j] = gk; bpos[j] = gp; }
      }
    }
    barrier_lgkm();

    // ---- phase C: reduce 128 bucket keys (wave 0), winner -> coords
    if (wave == 0) {
      unsigned long long k1 = bkey[lane], k2 = bkey[64 + lane];
      int p1 = bpos[lane], p2 = bpos[64 + lane];
      if (k2 > k1) { k1 = k2; p1 = p2; }
      dpp_max_pair<0x111, 0xF>(k1, p1);   // row_shr:1
      dpp_max_pair<0x112, 0xF>(k1, p1);   // row_shr:2
      dpp_max_pair<0x114, 0xF>(k1, p1);   // row_shr:4
      dpp_max_pair<0x118, 0xF>(k1, p1);   // row_shr:8
      dpp_max_pair<0x142, 0xA>(k1, p1);   // row_bcast:15 -> rows 1,3
      dpp_max_pair<0x143, 0xC>(k1, p1);   // row_bcast:31 -> rows 2,3
      if (lane == 63) { skey[parity] = k1; sposl[parity] = p1; }
    }
    barrier_lgkm();

    unsigned long long KW = skey[parity];
    int PW = sposl[parity];
    far = (int)(~(unsigned)(KW & 0xFFFFFFFFull));
    float4 c4 = sp4[PW];
    cx = c4.x; cy = c4.y; cz = c4.z;
  }
  __syncthreads();                                   // full drain before endgame

  // final 32 selections + full progress
  if (wave == 0 && lane < 32) {
    int tt = 992 + lane;
    float4 h = ring[tt & 63];
    int gidx = (b << 10) + tt;
    out[OUT_FPS + b * 1024 + tt] = h.w;
    out[b * 3072 + tt]           = h.x;
    out[b * 3072 + 1024 + tt]    = h.y;
    out[b * 3072 + 2048 + tt]    = h.z;
    astore64(&nxA[gidx],
             ((unsigned long long)__float_as_uint(h.x) << 32) | __float_as_uint(h.y));
    astore64(&nxB[gidx],
             ((unsigned long long)__float_as_uint(h.z) << 32) | (unsigned)((int)h.w + 1));
    if (lane == 0)
      __hip_atomic_store(&ctrl->prog[b], 1024, __ATOMIC_RELAXED, SCOPE);
  }
}

// ---------------------------------------------------------------- transpose [B,64,N] -> [B,N,64]
__device__ void tp_role(int bid, const float* __restrict__ pts, float* __restrict__ ptt,
                        Ctrl* ctrl, void* smem)
{
  float* tile = (float*)smem;            // [64*65]
  const int b  = bid >> 7;
  const int n0 = (bid & 127) * 64;
  const float* pb = pts + (size_t)b * D * NPTS;
#pragma unroll
  for (int i = 0; i < 8; i++) {
    int s = threadIdx.x + i * 512;
    int nl = s & 63, d = s >> 6;
    tile[d * 65 + nl] = pb[(size_t)d * NPTS + n0 + nl];
  }
  __syncthreads();
  float* ob = ptt + ((size_t)b * NPTS + n0) * D;
#pragma unroll
  for (int i = 0; i < 8; i++) {
    int s = threadIdx.x + i * 512;
    int dl = s & 63, nl = s >> 6;
    ob[(size_t)nl * D + dl] = tile[dl * 65 + nl];
  }
  __syncthreads();                                      // drain stores block-wide
  if (threadIdx.x == 0)                                 // RELEASE: waitcnt + wbl2, once
    __hip_atomic_fetch_add(&ctrl->tp_done[b], 1, __ATOMIC_RELEASE, SCOPE);
}

// ---------------------------------------------------------------- persistent worker:
// 16 centroids end-to-end: wait on per-batch progress counter -> guarded nx
// reads -> KNN (32 thr/cent) -> weightnet+feat (in LDS) -> agg -> 16x128 GEMM.
__device__ void worker_role(int u, const float* __restrict__ xyz,
                            const unsigned long long* __restrict__ nxA,
                            const unsigned long long* __restrict__ nxB,
                            const float* __restrict__ ptt,
                            const float* __restrict__ w1, const float* __restrict__ b1,
                            const float* __restrict__ w2, const float* __restrict__ b2,
                            const float* __restrict__ w3, const float* __restrict__ b3,
                            const float* __restrict__ lin_w, const float* __restrict__ lin_b,
                            float* __restrict__ agg, float* __restrict__ out,
                            Ctrl* ctrl, void* smem)
{
  const int tid = threadIdx.x;
  const int b   = u & 7;               // chunk-major: ticket order == readiness order
  const int q   = u >> 3;
  const int c0  = q * 16;
  const int cbase = (b << 10) + c0;

  unsigned long long* s_k = (unsigned long long*)smem;   // [16][545] u64, 69760 B
  float* s_cc = (float*)((char*)smem + 69760);           // [16][4]
  int*   s_nk = (int*)((char*)smem + 70016);             // [16][16]

  // ---- wait: single poller on per-batch progress counter, backoff sleep
  if (tid == 0) {
    const int need = c0 + 16;
    int p;
    while ((p = __hip_atomic_load(&ctrl->prog[b], __ATOMIC_RELAXED, SCOPE)) < need) {
      if (need - p > 64) __builtin_amdgcn_s_sleep(127);
      else               __builtin_amdgcn_s_sleep(16);
    }
  }
  __syncthreads();

  // one-shot guarded reads (prog is a hint; nx flags are the real guard)
  if (tid < 16) {
    unsigned long long Bv, Av;
    while ((unsigned)((Bv = aload64(&nxB[cbase + tid])) & 0xFFFFFFFFull) == 0u)
      __builtin_amdgcn_s_sleep(2);
    while ((Av = aload64(&nxA[cbase + tid])) == 0ull)
      __builtin_amdgcn_s_sleep(1);
    s_cc[tid * 4 + 0] = __uint_as_float((unsigned)(Av >> 32));
    s_cc[tid * 4 + 1] = __uint_as_float((unsigned)(Av & 0xFFFFFFFFull));
    s_cc[tid * 4 + 2] = __uint_as_float((unsigned)(Bv >> 32));
  }
  __syncthreads();

  // ---- KNN: 32 threads/cent, 256 pts each, exact reference arithmetic
  {
#pragma clang fp contract(off)
    const int cl    = tid >> 5;
    const int chunk = tid & 31;
    const float* xb = xyz + (size_t)b * 3 * NPTS;
    const float cx = s_cc[cl * 4 + 0];
    const float cy = s_cc[cl * 4 + 1];
    const float cz = s_cc[cl * 4 + 2];

    float nd[16]; int ni[16];
#pragma unroll
    for (int k = 0; k < 16; k++) { nd[k] = 3.4e38f; ni[k] = 0x7FFFFFFF; }

    for (int jj = 0; jj < 256; jj++) {
      int j = jj * 32 + chunk;
      float dx = xb[j] - cx, dy = xb[NPTS + j] - cy, dz = xb[2 * NPTS + j] - cz;
      float d  = (dx * dx + dy * dy) + dz * dz;
      float cv = d; int iv = j;
#pragma unroll
      for (int k = 0; k < 16; k++) {     // branchless sorted insertion (strict <)
        bool sw = cv < nd[k];
        float tv = nd[k]; int ti = ni[k];
        nd[k] = sw ? cv : tv;  ni[k] = sw ? iv : ti;
        cv    = sw ? tv : cv;  iv    = sw ? ti : iv;
      }
    }
#pragma unroll
    for (int k = 0; k < 16; k++)
      s_k[cl * 545 + chunk * 17 + k] =
          ((unsigned long long)__float_as_uint(nd[k]) << 32) | (unsigned)ni[k];
    s_k[cl * 545 + chunk * 17 + 16] = ~0ull;   // sentinel
  }
  __syncthreads();

  if (tid < 16) {                        // merge: 16 rounds of 32-way tournament (u64 min)
    int pos[32];
#pragma unroll
    for (int c = 0; c < 32; c++) pos[c] = 0;
    for (int r = 0; r < 16; r++) {
      unsigned long long bk = ~0ull; int bc = 0;
#pragma unroll
      for (int c = 0; c < 32; c++) {
        unsigned long long kv = s_k[tid * 545 + c * 17 + pos[c]];
        if (kv < bk) { bk = kv; bc = c; }
      }
#pragma unroll
      for (int c = 0; c < 32; c++) pos[c] += (c == bc);
      s_nk[tid * 16 + r] = (int)(bk & 0xFFFFFFFFull);
    }
  }
  if (tid == 0)                          // ptt ready? (relaxed; producer released)
    while (__hip_atomic_load(&ctrl->tp_done[b], __ATOMIC_RELAXED, SCOPE) < 128)
      __builtin_amdgcn_s_sleep(8);
  __syncthreads();

  // ---- feat: 8 waves x 2 iterations (one centroid per wave per iter)
  float* s_wts = (float*)smem;           // [8][272] (s_k region dead)
  float* s_off = s_wts + 8 * 272;        // [8][48]
  const int wv   = tid >> 6;
  const int lane = tid & 63;

  for (int it = 0; it < 2; it++) {
    const int cl2  = it * 8 + wv;        // 0..15
    const int csel = cbase + cl2;
    if (lane < 16) {
      int nk = s_nk[cl2 * 16 + lane];
      const float* xb = xyz + (size_t)b * 3 * NPTS;
      float ox = xb[nk]            - s_cc[cl2 * 4 + 0];
      float oy = xb[NPTS + nk]     - s_cc[cl2 * 4 + 1];
      float oz = xb[2 * NPTS + nk] - s_cc[cl2 * 4 + 2];
      s_off[wv * 48 + lane * 3 + 0] = ox;
      s_off[wv * 48 + lane * 3 + 1] = oy;
      s_off[wv * 48 + lane * 3 + 2] = oz;
      float h1[8], h2[8];
#pragma unroll
      for (int j = 0; j < 8; j++)
        h1[j] = fmaxf(0.f, ox * w1[j] + oy * w1[8 + j] + oz * w1[16 + j] + b1[j]);
#pragma unroll
      for (int j = 0; j < 8; j++) {
        float a = b2[j];
#pragma unroll
        for (int i = 0; i < 8; i++) a = fmaf(h1[i], w2[i * 8 + j], a);
        h2[j] = fmaxf(0.f, a);
      }
#pragma unroll
      for (int w = 0; w < 16; w++) {
        float a = b3[w];
#pragma unroll
        for (int i = 0; i < 8; i++) a = fmaf(h2[i], w3[i * 16 + w], a);
        s_wts[wv * 272 + lane * 17 + w] = fmaxf(0.f, a);
      }
    }
    __syncthreads();

    // gather point-feature channel d = lane for all 16 neighbors
    float f[16];
#pragma unroll
    for (int k = 0; k < 16; k++) {
      int nk = s_nk[cl2 * 16 + k];
      f[k] = ptt[((size_t)b * NPTS + nk) * D + lane];
    }
    float acc[16];
#pragma unroll
    for (int w = 0; w < 16; w++) acc[w] = 0.f;
#pragma unroll
    for (int k = 0; k < 16; k++) {
#pragma unroll
      for (int w = 0; w < 16; w++)
        acc[w] = fmaf(f[k], s_wts[wv * 272 + k * 17 + w], acc[w]);
    }
    float* arow = agg + (size_t)csel * (CIN * WN) + (3 + lane) * 16;
#pragma unroll
    for (int qq = 0; qq < 4; qq++) {
      float4 v = make_float4(acc[4 * qq], acc[4 * qq + 1], acc[4 * qq + 2], acc[4 * qq + 3]);
      *(float4*)(arow + 4 * qq) = v;
    }
    if (lane < 48) {                     // xyz-offset channels c = 0..2
      int c = lane >> 4, w = lane & 15;
      float a = 0.f;
#pragma unroll
      for (int k = 0; k < 16; k++)
        a = fmaf(s_off[wv * 48 + k * 3 + c], s_wts[wv * 272 + k * 17 + w], a);
      agg[(size_t)csel * (CIN * WN) + c * 16 + w] = a;
    }
    __syncthreads();                     // drains agg stores; frees s_wts for next iter
  }

  // ---- GEMM: rows [cbase, cbase+16) x 128 cols, K = 1072 (agg is L2-hot)
  float* a_t = (float*)smem;             // [16][17]
  float* b_t = a_t + 16 * 17;            // [16][128]
  float acc2[2][2] = {};
  for (int kt = 0; kt < 67; kt++) {
    const int k0 = kt * 16;
    if (tid < 256) {
      int r = tid & 15, kk = tid >> 4;
      a_t[kk * 17 + r] = agg[(size_t)(cbase + r) * (CIN * WN) + k0 + kk];
    }
#pragma unroll
    for (int i = 0; i < 4; i++) {
      int idx = tid + i * 512;
      int c = idx & 127, kk = idx >> 7;
      b_t[kk * 128 + c] = lin_w[(size_t)(k0 + kk) * OUTC + c];
    }
    __syncthreads();
#pragma unroll
    for (int kk = 0; kk < 16; kk++) {
      float a0 = a_t[kk * 17 + wv * 2];        // wave-uniform -> LDS broadcast
      float a1 = a_t[kk * 17 + wv * 2 + 1];
      float bv0 = b_t[kk * 128 + lane * 2];    // stride-2 -> conflict-free
      float bv1 = b_t[kk * 128 + lane * 2 + 1];
      acc2[0][0] = fmaf(a0, bv0, acc2[0][0]);
      acc2[0][1] = fmaf(a0, bv1, acc2[0][1]);
      acc2[1][0] = fmaf(a1, bv0, acc2[1][0]);
      acc2[1][1] = fmaf(a1, bv1, acc2[1][1]);
    }
    __syncthreads();
  }
#pragma unroll
  for (int j = 0; j < 2; j++) {
#pragma unroll
    for (int cc = 0; cc < 2; cc++) {
      int ss = c0 + wv * 2 + j;                // centroid index within batch
      int C  = lane * 2 + cc;
      float v = acc2[j][cc] + lin_b[C];
      v = v > 0.f ? v : 0.1f * v;
      out[OUT_MAIN + ((size_t)(b * OUTC + C)) * 1024 + ss] = v;
    }
  }
}

// ---------------------------------------------------------------- mega kernel
__global__ __launch_bounds__(512)
void mega_kernel(const float* __restrict__ xyz, const float* __restrict__ pts,
                 const float* __restrict__ w1, const float* __restrict__ b1,
                 const float* __restrict__ w2, const float* __restrict__ b2,
                 const float* __restrict__ w3, const float* __restrict__ b3,
                 const float* __restrict__ lin_w, const float* __restrict__ lin_b,
                 float* __restrict__ out, unsigned long long* __restrict__ nxA,
                 unsigned long long* __restrict__ nxB,
                 float* __restrict__ ptt, float* __restrict__ agg, Ctrl* ctrl)
{
  __shared__ __align__(16) unsigned long long smem[19232];   // 153856 B union
  __shared__ int s_ticket;
  if (threadIdx.x == 0)
    s_ticket = __hip_atomic_fetch_add(&ctrl->ticket, 1, __ATOMIC_RELAXED, SCOPE);
  __syncthreads();
  const int tk = s_ticket;

  if (tk < T_TP)
    fps_role(tk, xyz, nxA, nxB, out, ctrl, smem);
  else if (tk < T_WK)
    tp_role(tk - T_TP, pts, ptt, ctrl, smem);
  else
    worker_role(tk - T_WK, xyz, nxA, nxB, ptt, w1, b1, w2, b2, w3, b3,
                lin_w, lin_b, agg, out, ctrl, smem);
}

// ---------------------------------------------------------------- launch
extern "C" void kernel_launch(void* const* d_in, const int* in_sizes, int n_in,
                              void* d_out, int out_size, void* d_ws, size_t ws_size,
                              hipStream_t stream) {
  const float* xyz    = (const float*)d_in[0];
  const float* points = (const float*)d_in[1];
  const float* w1     = (const float*)d_in[2];
  const float* b1     = (const float*)d_in[3];
  const float* w2     = (const float*)d_in[4];
  const float* b2     = (const float*)d_in[5];
  const float* w3     = (const float*)d_in[6];
  const float* b3     = (const float*)d_in[7];
  const float* lin_w  = (const float*)d_in[8];
  const float* lin_b  = (const float*)d_in[9];
  float* out = (float*)d_out;
  char*  ws  = (char*)d_ws;

  Ctrl* ctrl              = (Ctrl*)(ws);                          // 4 KB
  unsigned long long* nxA = (unsigned long long*)(ws + 4096);     // [8192] 64 KB
  unsigned long long* nxB = (unsigned long long*)(ws + 69632);    // [8192] 64 KB
  float* ptt              = (float*)(ws + 1048576);               // [8,8192,64] 16 MiB
  float* agg              = (float*)(ws + 17825792);              // [8192,1072] ~33.5 MiB

  hipMemsetAsync(ws, 0, 135168, stream);   // ctrl + nxA + nxB
  mega_kernel<<<NBLK, 512, 0, stream>>>(xyz, points, w1, b1, w2, b2, w3, b3,
                                        lin_w, lin_b, out, nxA, nxB, ptt, agg, ctrl);
}

// Round 11
// 1564.838 us; speedup vs baseline: 1.2698x; 1.2698x over previous
//
#include <hip/hip_runtime.h>
#include <hip/hip_bf16.h>

#define NPTS   8192
#define NBATCH 8
#define S      1024
#define K      16
#define D      64
#define CIN    67
#define WN     16
#define OUTC   128

// d_out layout (floats): [0,24576) new_xyz [B,3,S]; [24576, 24576+1048576) out [B,128,S];
// [1073152, 1081344) fps_idx as float [B,S]
#define OUT_MAIN 24576
#define OUT_FPS  1073152

// ticket-role boundaries (arrival order == topological order; workers are
// readiness-ordered: unit u -> batch u&7, chunk u>>3)
#define T_FPS   0
#define T_TP    8
#define T_WK    1032
#define NBLK    1544

#define SCOPE __HIP_MEMORY_SCOPE_AGENT

typedef unsigned long long u64;

struct Ctrl {
  int ticket;
  int pad0[31];
  int tp_done[8];      // transpose blocks done per batch (128 = all)
  int pad1[24];
  int prog[8];         // FPS publication progress (centroids) per batch
};

__device__ __forceinline__ u64 aload64(const u64* p) {
  return __hip_atomic_load(p, __ATOMIC_RELAXED, SCOPE);
}
__device__ __forceinline__ void astore64(u64* p, u64 v) {
  __hip_atomic_store(p, v, __ATOMIC_RELAXED, SCOPE);
}

// Block barrier waiting only on LDS ops (publication stores stay in flight).
__device__ __forceinline__ void barrier_lgkm() {
  asm volatile("s_waitcnt lgkmcnt(0)\n\ts_barrier" ::: "memory");
}

// DPP pair-max step: (key,pos) accumulate toward lane 63. bound_ctrl=true ->
// invalid lanes contribute key=0 (never wins: key low32 = ~idx > 0 always).
template <int CTRL, int RM>
__device__ __forceinline__ void dpp_max_pair(u64& key, int& pos) {
  int lo = __builtin_amdgcn_update_dpp(0, (int)(unsigned)(key & 0xFFFFFFFFull), CTRL, RM, 0xF, true);
  int hi = __builtin_amdgcn_update_dpp(0, (int)(unsigned)(key >> 32),           CTRL, RM, 0xF, true);
  int op = __builtin_amdgcn_update_dpp(0, pos,                                  CTRL, RM, 0xF, true);
  u64 o = ((u64)(unsigned)hi << 32) | (unsigned)lo;
  if (o > key) { key = o; pos = op; }
}

// ---------------------------------------------------------------- FPS producer
// Exact bucketed FPS, conflict-free SoA LDS layout. Points counting-sorted
// into 128 spatially-coherent buckets of 64. Per iter:
//  A: 128 threads test bucket lower-bound vs bucket max-dist (exact skip:
//     margin 1e-6 >> 8-ulp fp error bound -> skipped bucket provably has
//     min(dist,d)=dist for every point); ballot-compact dirty list (no atomics).
//  B: one dirty bucket per wave per round, ONE POINT PER LANE (lane-stride-1
//     b32 -> conflict-free); 6-step DPP pair-max -> bkey/bpos.
//  C: every wave redundantly reduces the 128 bucket keys (no 3rd barrier),
//     __shfl(...,63) broadcast, winner coords via broadcast LDS read.
// Keys are (dist_bits<<32)|~orig_idx -- exact reference tie-break (max dist,
// then lowest index). Outputs stream via 64-deep ring, flushed every 32 iters
// fire-and-forget (lgkm-only barriers never drain them).
__device__ void fps_role(int b, const float* __restrict__ xyz,
                         u64* __restrict__ nxA, u64* __restrict__ nxB,
                         float* __restrict__ out, Ctrl* ctrl, void* smem)
{
#pragma clang fp contract(off)
  char* bp = (char*)smem;
  float*          sx   = (float*)bp;                     // [8192] 32 KB
  float*          sy   = (float*)(bp + 32768);           // [8192]
  float*          sz   = (float*)(bp + 65536);           // [8192]
  float*          sd   = (float*)(bp + 98304);           // [8192]
  unsigned short* sidx = (unsigned short*)(bp + 131072); // [8192] 16 KB
  float*          bbox = (float*)(bp + 147456);          // [128*6] 3072 B
  u64*            bkey = (u64*)(bp + 150528);            // [128] 1024 B
  int*            bpos = (int*)(bp + 151552);            // [128] 512 B
  int*            dlist= (int*)(bp + 152064);            // [128] two halves @0,@64
  int*            cnt  = (int*)(bp + 152576);            // [2]
  float4*         ring = (float4*)(bp + 152624);         // [64] 1024 B -> ends 153648
  // init-only overlays (regions rewritten before the loop):
  int* hist = (int*)(bp + 147456);                       // [512]
  int* offs = (int*)(bp + 149504);                       // [512]

  const int tid  = threadIdx.x;
  const int wave = tid >> 6;
  const int lane = tid & 63;
  const float* xb = xyz + (size_t)b * 3 * NPTS;

  // ---- init: load, block bbox, grid-cell counting sort, bucket bboxes
  float px[16], py[16], pz[16];
  int   cid[16];
#pragma unroll
  for (int i = 0; i < 16; i++) {
    int n = i * 512 + tid;
    px[i] = xb[n]; py[i] = xb[NPTS + n]; pz[i] = xb[2 * NPTS + n];
  }
  float mnx = px[0], mxx = px[0], mny = py[0], mxy = py[0], mnz = pz[0], mxz = pz[0];
#pragma unroll
  for (int i = 1; i < 16; i++) {
    mnx = fminf(mnx, px[i]); mxx = fmaxf(mxx, px[i]);
    mny = fminf(mny, py[i]); mxy = fmaxf(mxy, py[i]);
    mnz = fminf(mnz, pz[i]); mxz = fmaxf(mxz, pz[i]);
  }
#pragma unroll
  for (int off = 1; off < 64; off <<= 1) {
    mnx = fminf(mnx, __shfl_xor(mnx, off)); mxx = fmaxf(mxx, __shfl_xor(mxx, off));
    mny = fminf(mny, __shfl_xor(mny, off)); mxy = fmaxf(mxy, __shfl_xor(mxy, off));
    mnz = fminf(mnz, __shfl_xor(mnz, off)); mxz = fmaxf(mxz, __shfl_xor(mxz, off));
  }
  if (lane == 0) {
    ring[wave]     = make_float4(mnx, mxx, mny, mxy);
    ring[8 + wave] = make_float4(mnz, mxz, 0.f, 0.f);
  }
  if (tid < 512) hist[tid] = 0;
  __syncthreads();
  float LX = ring[0].x, HX = ring[0].y, LY = ring[0].z, HY = ring[0].w;
  float LZ = ring[8].x, HZ = ring[8].y;
#pragma unroll
  for (int w = 1; w < 8; w++) {
    LX = fminf(LX, ring[w].x); HX = fmaxf(HX, ring[w].y);
    LY = fminf(LY, ring[w].z); HY = fmaxf(HY, ring[w].w);
    LZ = fminf(LZ, ring[8 + w].x); HZ = fmaxf(HZ, ring[8 + w].y);
  }
  const float scx = 7.999f / fmaxf(HX - LX, 1e-30f);
  const float scy = 7.999f / fmaxf(HY - LY, 1e-30f);
  const float scz = 7.999f / fmaxf(HZ - LZ, 1e-30f);
#pragma unroll
  for (int i = 0; i < 16; i++) {
    int ix = min(7, max(0, (int)((px[i] - LX) * scx)));
    int iy = min(7, max(0, (int)((py[i] - LY) * scy)));
    int iz = min(7, max(0, (int)((pz[i] - LZ) * scz)));
    cid[i] = (iz << 6) | (iy << 3) | ix;
    atomicAdd(&hist[cid[i]], 1);
  }
  __syncthreads();
  if (tid < 512) {                       // serial exclusive prefix (once)
    int s = 0;
    for (int k = 0; k < tid; k++) s += hist[k];
    offs[tid] = s;
  }
  __syncthreads();
#pragma unroll
  for (int i = 0; i < 16; i++) {
    int slot = atomicAdd(&offs[cid[i]], 1);
    sx[slot] = px[i]; sy[slot] = py[i]; sz[slot] = pz[i];
    sd[slot] = 1e10f;
    sidx[slot] = (unsigned short)(i * 512 + tid);
  }
  __syncthreads();
  if (tid < 128) {                       // bucket bboxes (rotated reads: stride 65)
    float lx = 3.4e38f, hx = -3.4e38f, ly = 3.4e38f, hy = -3.4e38f;
    float lz = 3.4e38f, hz = -3.4e38f;
    for (int m = 0; m < 64; m++) {
      int p = tid * 64 + ((m + tid) & 63);
      float X = sx[p], Y = sy[p], Z = sz[p];
      lx = fminf(lx, X); hx = fmaxf(hx, X);
      ly = fminf(ly, Y); hy = fmaxf(hy, Y);
      lz = fminf(lz, Z); hz = fmaxf(hz, Z);
    }
    bbox[tid * 6 + 0] = lx; bbox[tid * 6 + 1] = hx;
    bbox[tid * 6 + 2] = ly; bbox[tid * 6 + 3] = hy;
    bbox[tid * 6 + 4] = lz; bbox[tid * 6 + 5] = hz;
    bkey[tid] = (u64)0x7F7FFFFFu << 32;  // maxd=3.4e38 -> force dirty at t=0
    bpos[tid] = 0;
  }
  __syncthreads();

  int far = 0;
  float cx = xb[0], cy = xb[NPTS], cz = xb[2 * NPTS];

  for (int t = 0; t < 1024; t++) {
    if (tid == (t & 511))                               // buffer result in LDS ring
      ring[t & 63] = make_float4(cx, cy, cz, (float)far);

    // flush previous 32 selections (fire-and-forget)
    if ((t & 31) == 0 && t > 0 && wave == 1 && lane < 32) {
      int tt = t - 32 + lane;
      float4 h = ring[tt & 63];
      int gidx = (b << 10) + tt;
      out[OUT_FPS + b * 1024 + tt] = h.w;
      out[b * 3072 + tt]           = h.x;
      out[b * 3072 + 1024 + tt]    = h.y;
      out[b * 3072 + 2048 + tt]    = h.z;
      astore64(&nxA[gidx],
               ((u64)__float_as_uint(h.x) << 32) | __float_as_uint(h.y));
      astore64(&nxB[gidx],
               ((u64)__float_as_uint(h.z) << 32) | (unsigned)((int)h.w + 1));
      if (lane == 0)
        __hip_atomic_store(&ctrl->prog[b], t, __ATOMIC_RELAXED, SCOPE);
    }

    // ---- phase A: exact bucket skip test + ballot compaction (waves 0..1)
    if (tid < 128) {
      const int half = tid >> 6;
      float maxd = __uint_as_float((unsigned)(bkey[tid] >> 32));
      float ux = fmaxf(0.f, fmaxf(bbox[tid * 6 + 0] - cx, cx - bbox[tid * 6 + 1]));
      float uy = fmaxf(0.f, fmaxf(bbox[tid * 6 + 2] - cy, cy - bbox[tid * 6 + 3]));
      float uz = fmaxf(0.f, fmaxf(bbox[tid * 6 + 4] - cz, cz - bbox[tid * 6 + 5]));
      float lb = (ux * ux + uy * uy) + uz * uz;
      bool dirty = lb * 0.999999f < maxd;   // conservative margin >> fp error
      u64 m = __ballot(dirty);
      int pre = __popcll(m & ((1ull << lane) - 1ull));
      if (dirty) dlist[half * 64 + pre] = tid;
      if (lane == 0) cnt[half] = (int)__popcll(m);
    }
    barrier_lgkm();

    // ---- phase B: one dirty bucket per wave per round, one point per lane
    const int Dn0 = cnt[0], Dn = Dn0 + cnt[1];
    for (int r = 0; r * 8 < Dn; r++) {
      int g = r * 8 + wave;                // wave-uniform
      if (g < Dn) {
        int j = (g < Dn0) ? dlist[g] : dlist[64 + g - Dn0];
        int p = (j << 6) | lane;           // lane-stride-1 -> conflict-free
        float X = sx[p], Y = sy[p], Z = sz[p], Dv = sd[p];
        float dx = X - cx, dy = Y - cy, dz = Z - cz;
        float d  = (dx * dx + dy * dy) + dz * dz;
        float nd = fminf(Dv, d);
        sd[p] = nd;
        unsigned oi = sidx[p];
        u64 key = ((u64)__float_as_uint(nd) << 32) | (unsigned)(~oi);
        int pos = p;
        dpp_max_pair<0x111, 0xF>(key, pos);
        dpp_max_pair<0x112, 0xF>(key, pos);
        dpp_max_pair<0x114, 0xF>(key, pos);
        dpp_max_pair<0x118, 0xF>(key, pos);
        dpp_max_pair<0x142, 0xA>(key, pos);
        dpp_max_pair<0x143, 0xC>(key, pos);
        if (lane == 63) { bkey[j] = key; bpos[j] = pos; }
      }
    }
    barrier_lgkm();

    // ---- phase C: every wave redundantly reduces 128 bucket keys (no barrier)
    u64 k1 = bkey[lane], k2 = bkey[64 + lane];
    int p1 = bpos[lane], p2 = bpos[64 + lane];
    if (k2 > k1) { k1 = k2; p1 = p2; }
    dpp_max_pair<0x111, 0xF>(k1, p1);
    dpp_max_pair<0x112, 0xF>(k1, p1);
    dpp_max_pair<0x114, 0xF>(k1, p1);
    dpp_max_pair<0x118, 0xF>(k1, p1);
    dpp_max_pair<0x142, 0xA>(k1, p1);
    dpp_max_pair<0x143, 0xC>(k1, p1);
    unsigned wlo = (unsigned)__shfl((int)(unsigned)(k1 & 0xFFFFFFFFull), 63);
    int pw = __shfl(p1, 63);
    far = (int)(~wlo);
    cx = sx[pw]; cy = sy[pw]; cz = sz[pw];   // broadcast LDS reads
  }
  __syncthreads();                                   // full drain before endgame

  // final 32 selections + full progress
  if (wave == 1 && lane < 32) {
    int tt = 992 + lane;
    float4 h = ring[tt & 63];
    int gidx = (b << 10) + tt;
    out[OUT_FPS + b * 1024 + tt] = h.w;
    out[b * 3072 + tt]           = h.x;
    out[b * 3072 + 1024 + tt]    = h.y;
    out[b * 3072 + 2048 + tt]    = h.z;
    astore64(&nxA[gidx],
             ((u64)__float_as_uint(h.x) << 32) | __float_as_uint(h.y));
    astore64(&nxB[gidx],
             ((u64)__float_as_uint(h.z) << 32) | (unsigned)((int)h.w + 1));
    if (lane == 0)
      __hip_atomic_store(&ctrl->prog[b], 1024, __ATOMIC_RELAXED, SCOPE);
  }
}

// ---------------------------------------------------------------- transpose [B,64,N] -> [B,N,64]
__device__ void tp_role(int bid, const float* __restrict__ pts, float* __restrict__ ptt,
                        Ctrl* ctrl, void* smem)
{
  float* tile = (float*)smem;            // [64*65]
  const int b  = bid >> 7;
  const int n0 = (bid & 127) * 64;
  const float* pb = pts + (size_t)b * D * NPTS;
#pragma unroll
  for (int i = 0; i < 8; i++) {
    int s = threadIdx.x + i * 512;
    int nl = s & 63, d = s >> 6;
    tile[d * 65 + nl] = pb[(size_t)d * NPTS + n0 + nl];
  }
  __syncthreads();
  float* ob = ptt + ((size_t)b * NPTS + n0) * D;
#pragma unroll
  for (int i = 0; i < 8; i++) {
    int s = threadIdx.x + i * 512;
    int dl = s & 63, nl = s >> 6;
    ob[(size_t)nl * D + dl] = tile[dl * 65 + nl];
  }
  __syncthreads();                                      // drain stores block-wide
  if (threadIdx.x == 0)                                 // RELEASE: waitcnt + wbl2, once
    __hip_atomic_fetch_add(&ctrl->tp_done[b], 1, __ATOMIC_RELEASE, SCOPE);
}

// ---------------------------------------------------------------- persistent worker:
// 16 centroids end-to-end: wait on per-batch progress counter -> guarded nx
// reads -> KNN (32 thr/cent) -> weightnet+feat (in LDS) -> agg -> 16x128 GEMM.
__device__ void worker_role(int u, const float* __restrict__ xyz,
                            const u64* __restrict__ nxA, const u64* __restrict__ nxB,
                            const float* __restrict__ ptt,
                            const float* __restrict__ w1, const float* __restrict__ b1,
                            const float* __restrict__ w2, const float* __restrict__ b2,
                            const float* __restrict__ w3, const float* __restrict__ b3,
                            const float* __restrict__ lin_w, const float* __restrict__ lin_b,
                            float* __restrict__ agg, float* __restrict__ out,
                            Ctrl* ctrl, void* smem)
{
  const int tid = threadIdx.x;
  const int b   = u & 7;               // chunk-major: ticket order == readiness order
  const int q   = u >> 3;
  const int c0  = q * 16;
  const int cbase = (b << 10) + c0;

  u64*   s_k  = (u64*)smem;                              // [16][545] u64, 69760 B
  float* s_cc = (float*)((char*)smem + 69760);           // [16][4]
  int*   s_nk = (int*)((char*)smem + 70016);             // [16][16]

  // ---- wait: single poller on per-batch progress counter, backoff sleep
  if (tid == 0) {
    const int need = c0 + 16;
    int p;
    while ((p = __hip_atomic_load(&ctrl->prog[b], __ATOMIC_RELAXED, SCOPE)) < need) {
      if (need - p > 64) __builtin_amdgcn_s_sleep(127);
      else               __builtin_amdgcn_s_sleep(16);
    }
  }
  __syncthreads();

  // one-shot guarded reads (prog is a hint; nx flags are the real guard)
  if (tid < 16) {
    u64 Bv, Av;
    while ((unsigned)((Bv = aload64(&nxB[cbase + tid])) & 0xFFFFFFFFull) == 0u)
      __builtin_amdgcn_s_sleep(2);
    while ((Av = aload64(&nxA[cbase + tid])) == 0ull)
      __builtin_amdgcn_s_sleep(1);
    s_cc[tid * 4 + 0] = __uint_as_float((unsigned)(Av >> 32));
    s_cc[tid * 4 + 1] = __uint_as_float((unsigned)(Av & 0xFFFFFFFFull));
    s_cc[tid * 4 + 2] = __uint_as_float((unsigned)(Bv >> 32));
  }
  __syncthreads();

  // ---- KNN: 32 threads/cent, 256 pts each, exact reference arithmetic
  {
#pragma clang fp contract(off)
    const int cl    = tid >> 5;
    const int chunk = tid & 31;
    const float* xb = xyz + (size_t)b * 3 * NPTS;
    const float cx = s_cc[cl * 4 + 0];
    const float cy = s_cc[cl * 4 + 1];
    const float cz = s_cc[cl * 4 + 2];

    float nd[16]; int ni[16];
#pragma unroll
    for (int k = 0; k < 16; k++) { nd[k] = 3.4e38f; ni[k] = 0x7FFFFFFF; }

    for (int jj = 0; jj < 256; jj++) {
      int j = jj * 32 + chunk;
      float dx = xb[j] - cx, dy = xb[NPTS + j] - cy, dz = xb[2 * NPTS + j] - cz;
      float d  = (dx * dx + dy * dy) + dz * dz;
      float cv = d; int iv = j;
#pragma unroll
      for (int k = 0; k < 16; k++) {     // branchless sorted insertion (strict <)
        bool sw = cv < nd[k];
        float tv = nd[k]; int ti = ni[k];
        nd[k] = sw ? cv : tv;  ni[k] = sw ? iv : ti;
        cv    = sw ? tv : cv;  iv    = sw ? ti : iv;
      }
    }
#pragma unroll
    for (int k = 0; k < 16; k++)
      s_k[cl * 545 + chunk * 17 + k] =
          ((u64)__float_as_uint(nd[k]) << 32) | (unsigned)ni[k];
    s_k[cl * 545 + chunk * 17 + 16] = ~0ull;   // sentinel
  }
  __syncthreads();

  if (tid < 16) {                        // merge: 16 rounds of 32-way tournament (u64 min)
    int pos[32];
#pragma unroll
    for (int c = 0; c < 32; c++) pos[c] = 0;
    for (int r = 0; r < 16; r++) {
      u64 bk = ~0ull; int bc = 0;
#pragma unroll
      for (int c = 0; c < 32; c++) {
        u64 kv = s_k[tid * 545 + c * 17 + pos[c]];
        if (kv < bk) { bk = kv; bc = c; }
      }
#pragma unroll
      for (int c = 0; c < 32; c++) pos[c] += (c == bc);
      s_nk[tid * 16 + r] = (int)(bk & 0xFFFFFFFFull);
    }
  }
  if (tid == 0)                          // ptt ready? (relaxed; producer released)
    while (__hip_atomic_load(&ctrl->tp_done[b], __ATOMIC_RELAXED, SCOPE) < 128)
      __builtin_amdgcn_s_sleep(8);
  __syncthreads();

  // ---- feat: 8 waves x 2 iterations (one centroid per wave per iter)
  float* s_wts = (float*)smem;           // [8][272] (s_k region dead)
  float* s_off = s_wts + 8 * 272;        // [8][48]
  const int wv   = tid >> 6;
  const int lane = tid & 63;

  for (int it = 0; it < 2; it++) {
    const int cl2  = it * 8 + wv;        // 0..15
    const int csel = cbase + cl2;
    if (lane < 16) {
      int nk = s_nk[cl2 * 16 + lane];
      const float* xb = xyz + (size_t)b * 3 * NPTS;
      float ox = xb[nk]            - s_cc[cl2 * 4 + 0];
      float oy = xb[NPTS + nk]     - s_cc[cl2 * 4 + 1];
      float oz = xb[2 * NPTS + nk] - s_cc[cl2 * 4 + 2];
      s_off[wv * 48 + lane * 3 + 0] = ox;
      s_off[wv * 48 + lane * 3 + 1] = oy;
      s_off[wv * 48 + lane * 3 + 2] = oz;
      float h1[8], h2[8];
#pragma unroll
      for (int j = 0; j < 8; j++)
        h1[j] = fmaxf(0.f, ox * w1[j] + oy * w1[8 + j] + oz * w1[16 + j] + b1[j]);
#pragma unroll
      for (int j = 0; j < 8; j++) {
        float a = b2[j];
#pragma unroll
        for (int i = 0; i < 8; i++) a = fmaf(h1[i], w2[i * 8 + j], a);
        h2[j] = fmaxf(0.f, a);
      }
#pragma unroll
      for (int w = 0; w < 16; w++) {
        float a = b3[w];
#pragma unroll
        for (int i = 0; i < 8; i++) a = fmaf(h2[i], w3[i * 16 + w], a);
        s_wts[wv * 272 + lane * 17 + w] = fmaxf(0.f, a);
      }
    }
    __syncthreads();

    // gather point-feature channel d = lane for all 16 neighbors
    float f[16];
#pragma unroll
    for (int k = 0; k < 16; k++) {
      int nk = s_nk[cl2 * 16 + k];
      f[k] = ptt[((size_t)b * NPTS + nk) * D + lane];
    }
    float acc[16];
#pragma unroll
    for (int w = 0; w < 16; w++) acc[w] = 0.f;
#pragma unroll
    for (int k = 0; k < 16; k++) {
#pragma unroll
      for (int w = 0; w < 16; w++)
        acc[w] = fmaf(f[k], s_wts[wv * 272 + k * 17 + w], acc[w]);
    }
    float* arow = agg + (size_t)csel * (CIN * WN) + (3 + lane) * 16;
#pragma unroll
    for (int qq = 0; qq < 4; qq++) {
      float4 v = make_float4(acc[4 * qq], acc[4 * qq + 1], acc[4 * qq + 2], acc[4 * qq + 3]);
      *(float4*)(arow + 4 * qq) = v;
    }
    if (lane < 48) {                     // xyz-offset channels c = 0..2
      int c = lane >> 4, w = lane & 15;
      float a = 0.f;
#pragma unroll
      for (int k = 0; k < 16; k++)
        a = fmaf(s_off[wv * 48 + k * 3 + c], s_wts[wv * 272 + k * 17 + w], a);
      agg[(size_t)csel * (CIN * WN) + c * 16 + w] = a;
    }
    __syncthreads();                     // drains agg stores; frees s_wts for next iter
  }

  // ---- GEMM: rows [cbase, cbase+16) x 128 cols, K = 1072 (agg is L2-hot)
  float* a_t = (float*)smem;             // [16][17]
  float* b_t = a_t + 16 * 17;            // [16][128]
  float acc2[2][2] = {};
  for (int kt = 0; kt < 67; kt++) {
    const int k0 = kt * 16;
    if (tid < 256) {
      int r = tid & 15, kk = tid >> 4;
      a_t[kk * 17 + r] = agg[(size_t)(cbase + r) * (CIN * WN) + k0 + kk];
    }
#pragma unroll
    for (int i = 0; i < 4; i++) {
      int idx = tid + i * 512;
      int c = idx & 127, kk = idx >> 7;
      b_t[kk * 128 + c] = lin_w[(size_t)(k0 + kk) * OUTC + c];
    }
    __syncthreads();
#pragma unroll
    for (int kk = 0; kk < 16; kk++) {
      float a0 = a_t[kk * 17 + wv * 2];        // wave-uniform -> LDS broadcast
      float a1 = a_t[kk * 17 + wv * 2 + 1];
      float bv0 = b_t[kk * 128 + lane * 2];    // stride-2 -> conflict-free
      float bv1 = b_t[kk * 128 + lane * 2 + 1];
      acc2[0][0] = fmaf(a0, bv0, acc2[0][0]);
      acc2[0][1] = fmaf(a0, bv1, acc2[0][1]);
      acc2[1][0] = fmaf(a1, bv0, acc2[1][0]);
      acc2[1][1] = fmaf(a1, bv1, acc2[1][1]);
    }
    __syncthreads();
  }
#pragma unroll
  for (int j = 0; j < 2; j++) {
#pragma unroll
    for (int cc = 0; cc < 2; cc++) {
      int ss = c0 + wv * 2 + j;                // centroid index within batch
      int C  = lane * 2 + cc;
      float v = acc2[j][cc] + lin_b[C];
      v = v > 0.f ? v : 0.1f * v;
      out[OUT_MAIN + ((size_t)(b * OUTC + C)) * 1024 + ss] = v;
    }
  }
}

// ---------------------------------------------------------------- mega kernel
__global__ __launch_bounds__(512)
void mega_kernel(const float* __restrict__ xyz, const float* __restrict__ pts,
                 const float* __restrict__ w1, const float* __restrict__ b1,
                 const float* __restrict__ w2, const float* __restrict__ b2,
                 const float* __restrict__ w3, const float* __restrict__ b3,
                 const float* __restrict__ lin_w, const float* __restrict__ lin_b,
                 float* __restrict__ out, u64* __restrict__ nxA, u64* __restrict__ nxB,
                 float* __restrict__ ptt, float* __restrict__ agg, Ctrl* ctrl)
{
  __shared__ __align__(16) u64 smem[19232];   // 153856 B union
  __shared__ int s_ticket;
  if (threadIdx.x == 0)
    s_ticket = __hip_atomic_fetch_add(&ctrl->ticket, 1, __ATOMIC_RELAXED, SCOPE);
  __syncthreads();
  const int tk = s_ticket;

  if (tk < T_TP)
    fps_role(tk, xyz, nxA, nxB, out, ctrl, smem);
  else if (tk < T_WK)
    tp_role(tk - T_TP, pts, ptt, ctrl, smem);
  else
    worker_role(tk - T_WK, xyz, nxA, nxB, ptt, w1, b1, w2, b2, w3, b3,
                lin_w, lin_b, agg, out, ctrl, smem);
}

// ---------------------------------------------------------------- launch
extern "C" void kernel_launch(void* const* d_in, const int* in_sizes, int n_in,
                              void* d_out, int out_size, void* d_ws, size_t ws_size,
                              hipStream_t stream) {
  const float* xyz    = (const float*)d_in[0];
  const float* points = (const float*)d_in[1];
  const float* w1     = (const float*)d_in[2];
  const float* b1     = (const float*)d_in[3];
  const float* w2     = (const float*)d_in[4];
  const float* b2     = (const float*)d_in[5];
  const float* w3     = (const float*)d_in[6];
  const float* b3     = (const float*)d_in[7];
  const float* lin_w  = (const float*)d_in[8];
  const float* lin_b  = (const float*)d_in[9];
  float* out = (float*)d_out;
  char*  ws  = (char*)d_ws;

  Ctrl* ctrl = (Ctrl*)(ws);                          // 4 KB
  u64*  nxA  = (u64*)(ws + 4096);                    // [8192] 64 KB
  u64*  nxB  = (u64*)(ws + 69632);                   // [8192] 64 KB
  float* ptt = (float*)(ws + 1048576);               // [8,8192,64] 16 MiB
  float* agg = (float*)(ws + 17825792);              // [8192,1072] ~33.5 MiB

  hipMemsetAsync(ws, 0, 135168, stream);   // ctrl + nxA + nxB
  mega_kernel<<<NBLK, 512, 0, stream>>>(xyz, points, w1, b1, w2, b2, w3, b3,
                                        lin_w, lin_b, out, nxA, nxB, ptt, agg, ctrl);
}